// Round 1
// baseline (431.452 us; speedup 1.0000x reference)
//
#include <hip/hip_runtime.h>
#include <math.h>

#define HH 1024
#define VV 50000

// butterfly reduce over the 64-lane wave: all lanes end with the total
__device__ __forceinline__ float wredsum(float v) {
#pragma unroll
    for (int o = 32; o > 0; o >>= 1) v += __shfl_xor(v, o);
    return v;
}

// ---------------------------------------------------------------------------
// K1: LSTM cell. One wave per hidden index j (grid 256 x 4 waves = 1024).
// gates[r] = W_ih[r]·e + b_ih[r] + W_hh[r]·h + b_hh[r],  r = g*H + j
// ---------------------------------------------------------------------------
__global__ __launch_bounds__(256) void lstm_kernel(
    const int* __restrict__ tok, const float* __restrict__ emb,
    const float* __restrict__ h0, const float* __restrict__ c0,
    const float* __restrict__ W_ih, const float* __restrict__ W_hh,
    const float* __restrict__ b_ih, const float* __restrict__ b_hh,
    float* __restrict__ out)  // d_out: [V logits][H h_new][H c_new]
{
    const int wid  = threadIdx.x >> 6;
    const int lane = threadIdx.x & 63;
    const int j    = blockIdx.x * 4 + wid;          // 0..1023
    const int t    = tok[0];                         // int64 low word (0 <= t < V)
    const float* e = emb + (size_t)t * HH;

    float4 ev[4], hv[4];
#pragma unroll
    for (int k = 0; k < 4; ++k) {
        const int idx = k * 256 + lane * 4;
        ev[k] = *(const float4*)(e  + idx);
        hv[k] = *(const float4*)(h0 + idx);
    }

    float gate[4];
#pragma unroll
    for (int g = 0; g < 4; ++g) {
        const float* wi = W_ih + (size_t)(g * HH + j) * HH;
        const float* wh = W_hh + (size_t)(g * HH + j) * HH;
        float acc = 0.f;
#pragma unroll
        for (int k = 0; k < 4; ++k) {
            const int idx = k * 256 + lane * 4;
            const float4 a = *(const float4*)(wi + idx);
            const float4 b = *(const float4*)(wh + idx);
            acc += a.x * ev[k].x + a.y * ev[k].y + a.z * ev[k].z + a.w * ev[k].w;
            acc += b.x * hv[k].x + b.y * hv[k].y + b.z * hv[k].z + b.w * hv[k].w;
        }
        gate[g] = wredsum(acc);
    }

    if (lane == 0) {
        const float gi = gate[0] + b_ih[0 * HH + j] + b_hh[0 * HH + j];
        const float gf = gate[1] + b_ih[1 * HH + j] + b_hh[1 * HH + j];
        const float gg = gate[2] + b_ih[2 * HH + j] + b_hh[2 * HH + j];
        const float go = gate[3] + b_ih[3 * HH + j] + b_hh[3 * HH + j];
        const float si = 1.f / (1.f + expf(-gi));
        const float sf = 1.f / (1.f + expf(-gf));
        const float so = 1.f / (1.f + expf(-go));
        const float cn = sf * c0[j] + si * tanhf(gg);
        const float hn = so * tanhf(cn);
        out[VV + j]      = hn;
        out[VV + HH + j] = cn;
    }
}

// ---------------------------------------------------------------------------
// K2: logits[r] = out_W[r]·h + out_b[r]. One wave per row, strided; writes
// logits into d_out[0:V) and a per-block max partial into pmax[blockIdx].
// ---------------------------------------------------------------------------
__global__ __launch_bounds__(256) void logits_kernel(
    const float* __restrict__ out_W, const float* __restrict__ out_b,
    const float* __restrict__ h,      // = d_out + V (written by K1)
    float* __restrict__ logits,       // = d_out
    float* __restrict__ pmax, int nwaves)
{
    __shared__ float smax[4];
    const int wid  = threadIdx.x >> 6;
    const int lane = threadIdx.x & 63;
    const int gw   = blockIdx.x * 4 + wid;

    float4 hv[4];
#pragma unroll
    for (int k = 0; k < 4; ++k)
        hv[k] = *(const float4*)(h + k * 256 + lane * 4);

    float m = -INFINITY;
    for (int r = gw; r < VV; r += nwaves) {
        const float* w = out_W + (size_t)r * HH;
        float acc = 0.f;
#pragma unroll
        for (int k = 0; k < 4; ++k) {
            const float4 a = *(const float4*)(w + k * 256 + lane * 4);
            acc += a.x * hv[k].x + a.y * hv[k].y + a.z * hv[k].z + a.w * hv[k].w;
        }
        const float v = wredsum(acc) + out_b[r];  // uniform across lanes
        if (lane == 0) logits[r] = v;
        m = fmaxf(m, v);
    }
    if (lane == 0) smax[wid] = m;
    __syncthreads();
    if (threadIdx.x == 0)
        pmax[blockIdx.x] = fmaxf(fmaxf(smax[0], smax[1]), fmaxf(smax[2], smax[3]));
}

// ---------------------------------------------------------------------------
// K3: single block — global max from pmax, then S = sum exp(logit - M),
// write logZ = M + log(S).
// ---------------------------------------------------------------------------
__global__ __launch_bounds__(1024) void logz_kernel(
    const float* __restrict__ logits, const float* __restrict__ pmax,
    int nblk, float* __restrict__ logz)
{
    __shared__ float red[1024];
    float m = -INFINITY;
    for (int i = threadIdx.x; i < nblk; i += 1024) m = fmaxf(m, pmax[i]);
    red[threadIdx.x] = m;
    __syncthreads();
    for (int s = 512; s > 0; s >>= 1) {
        if (threadIdx.x < s)
            red[threadIdx.x] = fmaxf(red[threadIdx.x], red[threadIdx.x + s]);
        __syncthreads();
    }
    m = red[0];
    __syncthreads();

    float s = 0.f;
    for (int v = threadIdx.x; v < VV; v += 1024) s += expf(logits[v] - m);
    red[threadIdx.x] = s;
    __syncthreads();
    for (int st = 512; st > 0; st >>= 1) {
        if (threadIdx.x < st) red[threadIdx.x] += red[threadIdx.x + st];
        __syncthreads();
    }
    if (threadIdx.x == 0) *logz = m + logf(red[0]);
}

// ---------------------------------------------------------------------------
// K4: logits[v] -= logZ  (in place in d_out)
// ---------------------------------------------------------------------------
__global__ __launch_bounds__(256) void sub_kernel(
    float* __restrict__ logits, const float* __restrict__ logz)
{
    const float lz = *logz;
    const int v = blockIdx.x * 256 + threadIdx.x;
    if (v < VV) logits[v] -= lz;
}

extern "C" void kernel_launch(void* const* d_in, const int* in_sizes, int n_in,
                              void* d_out, int out_size, void* d_ws, size_t ws_size,
                              hipStream_t stream) {
    const int*   tok   = (const int*)  d_in[0];
    const float* h0    = (const float*)d_in[1];
    const float* c0    = (const float*)d_in[2];
    // d_in[3] encoder_outputs — dead code, never read
    const float* emb   = (const float*)d_in[4];
    // d_in[5..8] attn_W, attn_b, comb_W, comb_b — dead code, never read
    const float* W_ih  = (const float*)d_in[9];
    const float* W_hh  = (const float*)d_in[10];
    const float* b_ih  = (const float*)d_in[11];
    const float* b_hh  = (const float*)d_in[12];
    const float* out_W = (const float*)d_in[13];
    const float* out_b = (const float*)d_in[14];

    float* out = (float*)d_out;

    const int NB = 1250;              // K2 blocks -> 5000 waves -> 10 rows/wave
    float* pmax = (float*)d_ws;       // [NB]
    float* logz = pmax + NB;          // [1]

    lstm_kernel<<<256, 256, 0, stream>>>(tok, emb, h0, c0, W_ih, W_hh, b_ih, b_hh, out);
    logits_kernel<<<NB, 256, 0, stream>>>(out_W, out_b, out + VV, out, pmax, NB * 4);
    logz_kernel<<<1, 1024, 0, stream>>>(out, pmax, NB, logz);
    sub_kernel<<<(VV + 255) / 256, 256, 0, stream>>>(out, logz);
}

// Round 2
// 413.304 us; speedup vs baseline: 1.0439x; 1.0439x over previous
//
#include <hip/hip_runtime.h>
#include <math.h>

#define HH 1024
#define VV 50000
#define NB2 1250           // K2 blocks: 5000 waves, exactly 10 rows/wave

// butterfly reduce over the 64-lane wave: all lanes end with the total
__device__ __forceinline__ float wredsum(float v) {
#pragma unroll
    for (int o = 32; o > 0; o >>= 1) v += __shfl_xor(v, o);
    return v;
}

// ---------------------------------------------------------------------------
// K1: LSTM cell. block = hidden index j (1024 blocks), wave = gate g (4 waves).
// 4 blocks/CU, each wave reads 2 rows (W_ih[g*H+j], W_hh[g*H+j]) = 8 KB.
// ---------------------------------------------------------------------------
__global__ __launch_bounds__(256) void lstm_kernel(
    const int* __restrict__ tok, const float* __restrict__ emb,
    const float* __restrict__ h0, const float* __restrict__ c0,
    const float* __restrict__ W_ih, const float* __restrict__ W_hh,
    const float* __restrict__ b_ih, const float* __restrict__ b_hh,
    float* __restrict__ out)  // d_out: [V logits][H h_new][H c_new]
{
    __shared__ float sg[4];
    const int g    = threadIdx.x >> 6;               // gate = wave id
    const int lane = threadIdx.x & 63;
    const int j    = blockIdx.x;                     // 0..1023
    const int t    = tok[0];                         // int64 low word
    const float* e = emb + (size_t)t * HH;

    const float* wi = W_ih + (size_t)(g * HH + j) * HH;
    const float* wh = W_hh + (size_t)(g * HH + j) * HH;

    float acc = 0.f;
#pragma unroll
    for (int k = 0; k < 4; ++k) {
        const int idx = k * 256 + lane * 4;
        const float4 a  = *(const float4*)(wi + idx);
        const float4 b  = *(const float4*)(wh + idx);
        const float4 ev = *(const float4*)(e  + idx);
        const float4 hv = *(const float4*)(h0 + idx);
        acc += a.x * ev.x + a.y * ev.y + a.z * ev.z + a.w * ev.w;
        acc += b.x * hv.x + b.y * hv.y + b.z * hv.z + b.w * hv.w;
    }
    acc = wredsum(acc);
    if (lane == 0) sg[g] = acc + b_ih[g * HH + j] + b_hh[g * HH + j];
    __syncthreads();

    if (threadIdx.x == 0) {
        const float si = 1.f / (1.f + expf(-sg[0]));
        const float sf = 1.f / (1.f + expf(-sg[1]));
        const float gg = tanhf(sg[2]);
        const float so = 1.f / (1.f + expf(-sg[3]));
        const float cn = sf * c0[j] + si * gg;
        const float hn = so * tanhf(cn);
        out[VV + j]      = hn;
        out[VV + HH + j] = cn;
    }
}

// ---------------------------------------------------------------------------
// K2: logits[r] = out_W[r]·h + out_b[r]; flash-style online (max, sumexp)
// per wave -> per block partial (m_b, s_b) into d_ws. 10 rows/wave, fully
// unrolled 5 x 2 rows for memory-level parallelism.
// ---------------------------------------------------------------------------
__global__ __launch_bounds__(256) void logits_kernel(
    const float* __restrict__ out_W, const float* __restrict__ out_b,
    const float* __restrict__ h,      // = d_out + V (written by K1)
    float* __restrict__ logits,       // = d_out
    float2* __restrict__ part)        // [NB2] (m_b, s_b)
{
    __shared__ float2 sp[4];
    const int wid  = threadIdx.x >> 6;
    const int lane = threadIdx.x & 63;
    const int gw   = blockIdx.x * 4 + wid;           // 0..4999

    float4 hv[4];
#pragma unroll
    for (int k = 0; k < 4; ++k)
        hv[k] = *(const float4*)(h + k * 256 + lane * 4);

    float m = -INFINITY, s = 0.f;
#pragma unroll
    for (int i = 0; i < 5; ++i) {
        const int r0 = gw + (2 * i)     * 5000;
        const int r1 = gw + (2 * i + 1) * 5000;
        const float* w0 = out_W + (size_t)r0 * HH;
        const float* w1 = out_W + (size_t)r1 * HH;
        float a0 = 0.f, a1 = 0.f;
#pragma unroll
        for (int k = 0; k < 4; ++k) {
            const int idx = k * 256 + lane * 4;
            const float4 x0 = *(const float4*)(w0 + idx);
            const float4 x1 = *(const float4*)(w1 + idx);
            a0 += x0.x * hv[k].x + x0.y * hv[k].y + x0.z * hv[k].z + x0.w * hv[k].w;
            a1 += x1.x * hv[k].x + x1.y * hv[k].y + x1.z * hv[k].z + x1.w * hv[k].w;
        }
        const float v0 = wredsum(a0) + out_b[r0];    // uniform across lanes
        const float v1 = wredsum(a1) + out_b[r1];
        if (lane == 0) { logits[r0] = v0; logits[r1] = v1; }
        // online softmax update (uniform, no divergence)
        const float nm = fmaxf(m, fmaxf(v0, v1));
        s = s * expf(m - nm) + expf(v0 - nm) + expf(v1 - nm);
        m = nm;
    }
    if (lane == 0) sp[wid] = make_float2(m, s);
    __syncthreads();
    if (threadIdx.x == 0) {
        float2 p = sp[0];
#pragma unroll
        for (int w = 1; w < 4; ++w) {
            const float2 q = sp[w];
            const float nm = fmaxf(p.x, q.x);
            p.y = p.y * expf(p.x - nm) + q.y * expf(q.x - nm);
            p.x = nm;
        }
        part[blockIdx.x] = p;
    }
}

// ---------------------------------------------------------------------------
// K3: one block of 256 — merge 1250 (m, s) partials -> logZ = M + log(S)
// ---------------------------------------------------------------------------
__global__ __launch_bounds__(256) void logz_kernel(
    const float2* __restrict__ part, int nblk, float* __restrict__ logz)
{
    __shared__ float2 red[256];
    float m = -INFINITY, s = 0.f;
    for (int i = threadIdx.x; i < nblk; i += 256) {
        const float2 q = part[i];
        const float nm = fmaxf(m, q.x);
        s = s * expf(m - nm) + q.y * expf(q.x - nm);
        m = nm;
    }
    red[threadIdx.x] = make_float2(m, s);
    __syncthreads();
    for (int st = 128; st > 0; st >>= 1) {
        if (threadIdx.x < st) {
            float2 p = red[threadIdx.x], q = red[threadIdx.x + st];
            const float nm = fmaxf(p.x, q.x);
            p.y = p.y * expf(p.x - nm) + q.y * expf(q.x - nm);
            p.x = nm;
            red[threadIdx.x] = p;
        }
        __syncthreads();
    }
    if (threadIdx.x == 0) *logz = red[0].x + logf(red[0].y);
}

// ---------------------------------------------------------------------------
// K4: logits[v] -= logZ  (in place in d_out)
// ---------------------------------------------------------------------------
__global__ __launch_bounds__(256) void sub_kernel(
    float* __restrict__ logits, const float* __restrict__ logz)
{
    const float lz = *logz;
    const int v = blockIdx.x * 256 + threadIdx.x;
    if (v < VV) logits[v] -= lz;
}

extern "C" void kernel_launch(void* const* d_in, const int* in_sizes, int n_in,
                              void* d_out, int out_size, void* d_ws, size_t ws_size,
                              hipStream_t stream) {
    const int*   tok   = (const int*)  d_in[0];
    const float* h0    = (const float*)d_in[1];
    const float* c0    = (const float*)d_in[2];
    // d_in[3] encoder_outputs — dead code, never read
    const float* emb   = (const float*)d_in[4];
    // d_in[5..8] attn_W, attn_b, comb_W, comb_b — dead code, never read
    const float* W_ih  = (const float*)d_in[9];
    const float* W_hh  = (const float*)d_in[10];
    const float* b_ih  = (const float*)d_in[11];
    const float* b_hh  = (const float*)d_in[12];
    const float* out_W = (const float*)d_in[13];
    const float* out_b = (const float*)d_in[14];

    float* out = (float*)d_out;

    float2* part = (float2*)d_ws;     // [NB2] (m_b, s_b) partials
    float*  logz = (float*)(part + NB2);

    lstm_kernel<<<1024, 256, 0, stream>>>(tok, emb, h0, c0, W_ih, W_hh, b_ih, b_hh, out);
    logits_kernel<<<NB2, 256, 0, stream>>>(out_W, out_b, out + VV, out, part);
    logz_kernel<<<1, 256, 0, stream>>>(part, NB2, logz);
    sub_kernel<<<(VV + 255) / 256, 256, 0, stream>>>(out, logz);
}